// Round 10
// baseline (107.541 us; speedup 1.0000x reference)
//
#include <hip/hip_runtime.h>

#define HSIZE 2048          // d-histogram buckets (d capped at RMAX+1 = 481 here)
#define CSH   7             // cell shift (128 px cells)
#define CSZ   128
#define MAXNC 4096          // global packed-cell capacity (this family: 17x30 = 510)
#define NCLDS 2048          // build LDS cell-array capacity
#define MAXLP 10176         // LDS-staged points (81408 B; 2 blocks/CU = 162816 <= 163840)
#define TPP   32            // threads per point
#define TPB   640           // 20 pts/block -> 500 blocks (<= 512 slots at 2/CU: ONE round)

// lcell4[c] = (off << 18) | ub18, ub18 = (maxScoreBits + 16383) >> 14  (round-UP quantize).
// Prune safety: ub <= pb>>14  =>  maxbits <= pb  (exact filter v.y > pb still applied per point).
// Requires off <= 16383 (n < 16384) and NC <= MAXNC; holds for this problem family.

// ---------------- K1: build (single workgroup) ----------------
__global__ __launch_bounds__(1024) void build_k(
    const int* __restrict__ kp, const float* __restrict__ sc,
    const int* __restrict__ nret_, const int* __restrict__ rows_, const int* __restrict__ cols_,
    int n, int* __restrict__ hist, int* __restrict__ meta,
    int* __restrict__ lcell4, int2* __restrict__ ppk, int* __restrict__ sidx,
    int* __restrict__ pbr, int* __restrict__ gscr) {
    __shared__ int2 lppL[MAXLP];
    __shared__ unsigned short sidxL[MAXLP];
    __shared__ int cnt[NCLDS];
    __shared__ int off_[NCLDS];
    __shared__ int cmx[NCLDS];
    __shared__ int wsum[8];
    int t = threadIdx.x, lane = t & 63, w = t >> 6;
    int rows = rows_[0], cols = cols_[0];
    int NCX = (cols + CSZ - 1) >> CSH;
    int NCY = (rows + CSZ - 1) >> CSH;
    int NC = NCX * NCY;
    bool fits = (NC <= NCLDS) && (n <= MAXLP);
    const int4* kp4 = (const int4*)kp;

    for (int i = t; i < HSIZE; i += 1024) hist[i] = 0;

    if (fits) {
        for (int i = t; i < NCLDS; i += 1024) { cnt[i] = 0; cmx[i] = 0; }
        __syncthreads();
        for (int i = t; i < n; i += 1024) {
            int4 k = kp4[i];
            int c = (k.z >> CSH) * NCX + (k.w >> CSH);
            atomicAdd(&cnt[c], 1);
            atomicMax(&cmx[c], __float_as_int(sc[i]));   // scores > 0: bit order == value order
        }
        __syncthreads();
        // exclusive scan over NCLDS=2048: first 512 threads, 4 cells each, shfl scans
        int s4 = 0, l0 = 0, l1 = 0, l2 = 0, l3 = 0, x = 0;
        if (t < 512) {
            int b = t * 4;
            l0 = cnt[b]; l1 = cnt[b + 1]; l2 = cnt[b + 2]; l3 = cnt[b + 3];
            s4 = l0 + l1 + l2 + l3;
            x = s4;
            for (int o = 1; o < 64; o <<= 1) { int v = __shfl_up(x, o); if (lane >= o) x += v; }
            if (lane == 63) wsum[w] = x;
        }
        __syncthreads();
        if (w == 0) {
            int v = (lane < 8) ? wsum[lane] : 0;
            for (int o = 1; o < 8; o <<= 1) { int u = __shfl_up(v, o); if (lane >= o) v += u; }
            if (lane < 8) wsum[lane] = v;               // inclusive wave totals
        }
        __syncthreads();
        if (t < 512) {
            int b = t * 4;
            int ex = ((w == 0) ? 0 : wsum[w - 1]) + x - s4;
            int o0 = ex, o1 = ex + l0, o2 = o1 + l1, o3 = o2 + l2;
            off_[b] = o0; off_[b + 1] = o1; off_[b + 2] = o2; off_[b + 3] = o3;
            cnt[b] = o0; cnt[b + 1] = o1; cnt[b + 2] = o2; cnt[b + 3] = o3;   // scatter cursor
        }
        __syncthreads();
        for (int i = t; i < n; i += 1024) {
            int4 k = kp4[i];
            int c = (k.z >> CSH) * NCX + (k.w >> CSH);
            int pos = atomicAdd(&cnt[c], 1);   // within-cell order nondeterministic; consumers commutative
            int2 v; v.x = (k.z << 16) | k.w; v.y = __float_as_int(sc[i]);
            lppL[pos] = v;
            sidxL[pos] = (unsigned short)i;
        }
        __syncthreads();
        // pbr pass (pixel-max + rep via min original index) + dump to global
        for (int j = t; j < n; j += 1024) {
            int2 v = lppL[j];
            int c = ((v.x >> 16) >> CSH) * NCX + ((v.x & 0xFFFF) >> CSH);
            int lo = off_[c], hi = cnt[c];     // cnt = end cursor after scatter
            int pmax = v.y; int mymi = sidxL[j]; int rep = 1;
            for (int u = lo; u < hi; ++u) {
                int2 wv = lppL[u];
                if (wv.x == v.x) {
                    if (wv.y > pmax) pmax = wv.y;
                    if ((int)sidxL[u] < mymi) rep = 0;
                }
            }
            pbr[j] = (int)(((unsigned)pmax) | (rep ? 0x80000000u : 0u));
            ppk[j] = v;
            sidx[j] = mymi;
        }
        for (int c = t; c < NC; c += 1024) {
            unsigned ub = ((unsigned)cmx[c] + 16383u) >> 14;
            lcell4[c] = (int)(((unsigned)off_[c] << 18) | ub);
        }
        if (t == 0) lcell4[NC] = (int)((unsigned)n << 18);
    } else {
        // correctness-only fallback (n < 16384, NC <= MAXNC): global scratch
        int* cntG = gscr; int* offG = gscr + MAXNC; int* cmxG = gscr + 2 * MAXNC;
        for (int i = t; i < NC; i += 1024) { cntG[i] = 0; cmxG[i] = 0; }
        __syncthreads();
        for (int i = t; i < n; i += 1024) {
            int4 k = kp4[i];
            int c = (k.z >> CSH) * NCX + (k.w >> CSH);
            atomicAdd(&cntG[c], 1);
            atomicMax(&cmxG[c], __float_as_int(sc[i]));
        }
        __syncthreads();
        if (t == 0) { int run = 0; for (int c = 0; c < NC; ++c) { offG[c] = run; run += cntG[c]; } }
        __syncthreads();
        for (int i = t; i < NC; i += 1024) cntG[i] = offG[i];
        __syncthreads();
        for (int i = t; i < n; i += 1024) {
            int4 k = kp4[i];
            int c = (k.z >> CSH) * NCX + (k.w >> CSH);
            int pos = atomicAdd(&cntG[c], 1);
            int2 v; v.x = (k.z << 16) | k.w; v.y = __float_as_int(sc[i]);
            ppk[pos] = v; sidx[pos] = i;
        }
        __syncthreads();
        for (int j = t; j < n; j += 1024) {
            int2 v = ppk[j];
            int c = ((v.x >> 16) >> CSH) * NCX + ((v.x & 0xFFFF) >> CSH);
            int lo = offG[c], hi = cntG[c];
            int pmax = v.y; int mymi = sidx[j]; int rep = 1;
            for (int u = lo; u < hi; ++u) {
                int2 wv = ppk[u];
                if (wv.x == v.x) { if (wv.y > pmax) pmax = wv.y; if (sidx[u] < mymi) rep = 0; }
            }
            pbr[j] = (int)(((unsigned)pmax) | (rep ? 0x80000000u : 0u));
        }
        __syncthreads();
        for (int c = t; c < NC; c += 1024) {
            unsigned ub = ((unsigned)cmxG[c] + 16383u) >> 14;
            lcell4[c] = (int)(((unsigned)offG[c] << 18) | ub);
        }
        if (t == 0) lcell4[NC] = (int)((unsigned)n << 18);
    }
    if (t == 0) {
        int nret = nret_[0];
        int mx = rows > cols ? rows : cols;
        int nr1 = nret > 1 ? nret : 1;
        int dvs = (int)sqrt((double)n / (double)nr1);   // Python int() truncation
        if (dvs < 1) dvs = 1;
        int high = mx / dvs; if (high < 1) high = 1;
        meta[0] = high / 2;                    // RMAX
        meta[1] = NCX;
        meta[2] = NCY;
    }
}

// ---------------- K2: query (32 thr/pt; points in LDS; packed cells via L1) ----------------
template<bool LDSP>
__global__ __launch_bounds__(TPB, 5) void query_k(
    const int* __restrict__ meta, const int* __restrict__ lcell4,
    const int2* __restrict__ ppk, const int* __restrict__ sidx,
    const int* __restrict__ pbr, int n, int* __restrict__ dd, int* __restrict__ hist) {
    __shared__ int2 lpp[LDSP ? MAXLP : 1];
    int t = threadIdx.x;
    int RMAX = meta[0], NCX = meta[1], NCY = meta[2];
    int gt = blockIdx.x * TPB + t;
    int q = gt >> 5, sub = gt & 31;
    bool act = q < n;

    // prefetch per-point globals BEFORE staging barrier
    int2 me; me.x = 0; me.y = 0;
    int idx = 0, pbrv = 0, lo = 0, hi = 0, y = 0, x = 0, cy = 0, cx = 0;
    if (act) {
        me = ppk[q];
        idx = sidx[q];
        pbrv = pbr[q];
        y = me.x >> 16; x = me.x & 0xFFFF;
        cy = y >> CSH;  cx = x >> CSH;
        int c0 = cy * NCX + cx;
        lo = (int)((unsigned)lcell4[c0] >> 18);
        hi = (int)((unsigned)lcell4[c0 + 1] >> 18);
    }
    if constexpr (LDSP) {
        int nh = n >> 1;
        const int4* s4 = (const int4*)ppk;
        int4* d4 = (int4*)lpp;
        for (int i = t; i < nh; i += TPB) d4[i] = s4[i];
        if ((n & 1) && t == 0) lpp[n - 1] = ppk[n - 1];
        __syncthreads();
    }
    if (act) {
        const int2* P = LDSP ? (const int2*)lpp : ppk;
        int pb  = pbrv & 0x7FFFFFFF;               // pixel-max score bits
        unsigned pbq = ((unsigned)pb) >> 14;       // quantized for cell prune
        int d = RMAX + 1;                          // "no higher within RMAX" sentinel
        for (int j = lo + sub; j < hi; j += TPP) { // ring 0: own cell (exact filter)
            int2 v = P[j];
            if (v.y > pb) {
                int dy = y - (v.x >> 16);    dy = dy < 0 ? -dy : dy;
                int dx = x - (v.x & 0xFFFF); dx = dx < 0 ? -dx : dx;
                int c = dy > dx ? dy : dx;
                if (c < d) d = c;
            }
        }
        d = min(d, __shfl_xor(d, 1));  d = min(d, __shfl_xor(d, 2));
        d = min(d, __shfl_xor(d, 4));  d = min(d, __shfl_xor(d, 8));
        d = min(d, __shfl_xor(d, 16));

        for (int R = 1;; ++R) {                    // expanding rings
            int LB = (R - 1) * CSZ + 1;
            if (LB >= d) break;                    // covers d == RMAX+1 cap too
            for (int e = sub; e < 8 * R; e += TPP) {
                int a, b;
                if (e < 2 * R + 1)      { a = -R; b = -R + e; }
                else if (e < 4 * R + 2) { a =  R; b = -R + (e - (2 * R + 1)); }
                else { int ss = e - (4 * R + 2); a = -R + 1 + (ss >> 1); b = (ss & 1) ? R : -R; }
                int ccy = cy + a, ccx = cx + b;
                if (ccy < 0 || ccy >= NCY || ccx < 0 || ccx >= NCX) continue;
                int cc = ccy * NCX + ccx;
                unsigned cm = (unsigned)lcell4[cc];        // one L1-hot 32-bit probe
                if ((cm & 0x3FFFFu) <= pbq) continue;      // conservative prune (safe)
                int jlo = (int)(cm >> 18);
                int jhi = (int)((unsigned)lcell4[cc + 1] >> 18);
                for (int j = jlo; j < jhi; ++j) {
                    int2 v = P[j];
                    if (v.y > pb) {
                        int dy = y - (v.x >> 16);    dy = dy < 0 ? -dy : dy;
                        int dx = x - (v.x & 0xFFFF); dx = dx < 0 ? -dx : dx;
                        int c = dy > dx ? dy : dx;
                        if (c < d) d = c;
                    }
                }
            }
            d = min(d, __shfl_xor(d, 1));  d = min(d, __shfl_xor(d, 2));
            d = min(d, __shfl_xor(d, 4));  d = min(d, __shfl_xor(d, 8));
            d = min(d, __shfl_xor(d, 16));
        }
        if (sub == 0) {
            dd[idx] = d;                                   // single writer per point
            if ((unsigned)pbrv >> 31)                      // pixel representative
                atomicAdd(&hist[d < HSIZE ? d : HSIZE - 1], 1);
        }
    }
}

// ---------------- K3: binary-search replica + ordered select (one block) ----------------
__global__ __launch_bounds__(1024) void finish_k(
    const int* __restrict__ kp, const float* __restrict__ sc,
    const int* __restrict__ dd, const int* __restrict__ hist,
    const int* __restrict__ nret_, const int* __restrict__ rows_, const int* __restrict__ cols_,
    int n, float* __restrict__ out) {
    __shared__ int suf[HSIZE + 1];
    __shared__ int wsuf[16];
    __shared__ int aux[1024];
    __shared__ int wtK[16], wtN[16];
    __shared__ int rsh;
    int t = threadIdx.x, lane = t & 63, w = t >> 6;

    // suffix sums of hist via shfl (3 barriers): suf[v] = # pixels with d >= v
    int b0 = hist[2 * t], b1 = hist[2 * t + 1];
    int s = b0 + b1;
    int x = s;
    for (int o = 1; o < 64; o <<= 1) { int v = __shfl_down(x, o); if (lane + o < 64) x += v; }
    if (lane == 0) wsuf[w] = x;
    __syncthreads();
    if (w == 0) {
        int v = (lane < 16) ? wsuf[lane] : 0;
        for (int o = 1; o < 16; o <<= 1) { int u = __shfl_down(v, o); if (lane + o < 16) v += u; }
        if (lane < 16) wsuf[lane] = v;             // inclusive suffix of wave totals
    }
    __syncthreads();
    int S = x + ((w < 15) ? wsuf[w + 1] : 0);
    suf[2 * t] = S;
    suf[2 * t + 1] = S - b0;
    if (t == 0) suf[HSIZE] = 0;
    __syncthreads();

    if (t == 0) {
        int nret = nret_[0];
        int rows = rows_[0], cols = cols_[0];
        int kmin = (int)llround((double)nret * (1.0 - 0.1));
        int kmax = (int)llround((double)nret * (1.0 + 0.1));
        int mx = rows > cols ? rows : cols;
        int nr1 = nret > 1 ? nret : 1;
        int dvs = (int)sqrt((double)n / (double)nr1);
        if (dvs < 1) dvs = 1;
        int high = mx / dvs; if (high < 1) high = 1;
        int low = 1, prev_k = -1, r_final = -1;
        bool found = false;
        while (true) {
            int k = (low + high) / 2;
            if (k == prev_k || low > high) break;
            int r = k / 2;                               // == k_odd // 2 for both parities
            int cnt = (r + 1 <= HSIZE) ? suf[r + 1] : 0;
            if (cnt >= kmin && cnt <= kmax) { r_final = r; found = true; break; }
            else if (cnt < kmin) high = k - 1;
            else low = k + 1;
            prev_k = k;
        }
        if (!found) {
            int kfb = prev_k > 0 ? prev_k : 1;
            r_final = kfb / 2;
        }
        rsh = r_final;
    }
    __syncthreads();
    int r = rsh;
    int nret = nret_[0];

    // total kept points m
    int c = 0;
    for (int i = t; i < n; i += 1024) c += (dd[i] > r) ? 1 : 0;
    aux[t] = c;
    __syncthreads();
    for (int st = 512; st > 0; st >>= 1) {
        if (t < st) aux[t] += aux[t + st];
        __syncthreads();
    }
    int m = aux[0];
    __syncthreads();

    // ordered selection: kept ascending, pad with non-kept ascending, truncate at nret
    unsigned long long lanemask = (lane == 0) ? 0ull : (~0ull >> (64 - lane));
    int runK = 0, runN = 0;
    for (int bb = 0; bb < n; bb += 1024) {
        int i = bb + t;
        bool valid = i < n;
        bool f  = valid && (dd[i] > r);
        bool nf = valid && !f;
        unsigned long long mk = __ballot(f);
        unsigned long long mn = __ballot(nf);
        int pk = __popcll(mk & lanemask);
        int pn = __popcll(mn & lanemask);
        if (lane == 0) { wtK[w] = __popcll(mk); wtN[w] = __popcll(mn); }
        __syncthreads();
        int exK = runK + pk, exN = runN + pn;
        for (int u = 0; u < w; ++u) { exK += wtK[u]; exN += wtN[u]; }
        int ctK = 0, ctN = 0;
        for (int u = 0; u < 16; ++u) { ctK += wtK[u]; ctN += wtN[u]; }
        __syncthreads();
        if (valid) {
            int slot = -1;
            if (f) {
                if (exK < nret) slot = exK;
            } else if (nf && m < nret && (m + exN) < nret) {
                slot = m + exN;
            }
            if (slot >= 0) {
                out[slot * 4 + 0] = (float)kp[i * 4 + 0];
                out[slot * 4 + 1] = (float)kp[i * 4 + 1];
                out[slot * 4 + 2] = (float)kp[i * 4 + 2];
                out[slot * 4 + 3] = (float)kp[i * 4 + 3];
                out[nret * 4 + slot] = sc[i];
            }
        }
        runK += ctK;
        runN += ctN;
    }
}

extern "C" void kernel_launch(void* const* d_in, const int* in_sizes, int n_in,
                              void* d_out, int out_size, void* d_ws, size_t ws_size,
                              hipStream_t stream) {
    const int*   kp   = (const int*)d_in[0];
    const float* sc   = (const float*)d_in[1];
    const int*   nret = (const int*)d_in[2];
    const int*   rows = (const int*)d_in[3];
    const int*   cols = (const int*)d_in[4];
    int n = in_sizes[1];                       // number of points

    int* hist   = (int*)d_ws;                  // 2048
    int* meta   = hist + HSIZE;                // 16
    int* lcell4 = meta + 16;                   // MAXNC+16
    int* gscr   = lcell4 + MAXNC + 16;         // 3*MAXNC (fallback scratch)
    int2* ppk   = (int2*)(gscr + 3 * MAXNC);   // n int2 (even int offset -> 8B aligned)
    int* sidx   = (int*)(ppk + n);             // n
    int* pbr    = sidx + n;                    // n
    int* dd     = pbr + n;                     // n
    float* out  = (float*)d_out;

    build_k<<<1, 1024, 0, stream>>>(kp, sc, nret, rows, cols, n,
                                    hist, meta, lcell4, ppk, sidx, pbr, gscr);
    int qblocks = (int)(((long long)n * TPP + TPB - 1) / TPB);   // 500 for n=10000
    if (n <= MAXLP)
        query_k<true><<<qblocks, TPB, 0, stream>>>(meta, lcell4, ppk, sidx, pbr, n, dd, hist);
    else
        query_k<false><<<qblocks, TPB, 0, stream>>>(meta, lcell4, ppk, sidx, pbr, n, dd, hist);
    finish_k<<<1, 1024, 0, stream>>>(kp, sc, dd, hist, nret, rows, cols, n, out);
}

// Round 11
// 95.165 us; speedup vs baseline: 1.1300x; 1.1300x over previous
//
#include <hip/hip_runtime.h>

#define HSIZE 2048          // d-histogram buckets
#define CSH   6             // cell shift (64 px cells)
#define CSZ   64
#define NCG   4096          // global cell-array capacity
#define NCLDS 2048          // LDS cell capacity (this family: 34x60 = 2040)
#define BLP   10176         // build LDS point capacity
#define QLP   10240         // query LDS point capacity (80 KB)
#define TPP   16            // threads per point, pass 1
#define TPB   640           // 40 pts/block -> 250 blocks: one round at 1 block/CU

// ---------------- K1: build (single workgroup) ----------------
// zero hist; counting-sort points into cells (ppk/sidx); per-cell max; per-point
// pixel-max|rep (pbr); meta = {RMAX, NCX, NCY}
__global__ __launch_bounds__(1024) void build_k(
    const int* __restrict__ kp, const float* __restrict__ sc,
    const int* __restrict__ nret_, const int* __restrict__ rows_, const int* __restrict__ cols_,
    int n, int* __restrict__ hist, int* __restrict__ meta,
    int* __restrict__ celloff, int* __restrict__ cellmax,
    int2* __restrict__ ppk, int* __restrict__ sidx, int* __restrict__ pbr,
    int* __restrict__ gscr) {
    __shared__ int2 lppL[BLP];
    __shared__ unsigned short sidxL[BLP];
    __shared__ int cnt[NCLDS];
    __shared__ int off_[NCLDS];
    __shared__ int cmx[NCLDS];
    __shared__ int wsum[8];
    int t = threadIdx.x, lane = t & 63, w = t >> 6;
    int rows = rows_[0], cols = cols_[0];
    int NCX = (cols + CSZ - 1) >> CSH;
    int NCY = (rows + CSZ - 1) >> CSH;
    int NC = NCX * NCY;
    bool fits = (NC <= NCLDS) && (n <= BLP);
    const int4* kp4 = (const int4*)kp;

    for (int i = t; i < HSIZE; i += 1024) hist[i] = 0;

    if (fits) {
        for (int i = t; i < NCLDS; i += 1024) { cnt[i] = 0; cmx[i] = 0; }
        __syncthreads();
        for (int i = t; i < n; i += 1024) {
            int4 k = kp4[i];
            int c = (k.z >> CSH) * NCX + (k.w >> CSH);
            atomicAdd(&cnt[c], 1);
            atomicMax(&cmx[c], __float_as_int(sc[i]));   // scores > 0: bit order == value order
        }
        __syncthreads();
        // exclusive scan over NCLDS=2048: first 512 threads, 4 cells each, shfl scans
        int s4 = 0, l0 = 0, l1 = 0, l2 = 0, l3 = 0, x = 0;
        if (t < 512) {
            int b = t * 4;
            l0 = cnt[b]; l1 = cnt[b + 1]; l2 = cnt[b + 2]; l3 = cnt[b + 3];
            s4 = l0 + l1 + l2 + l3;
            x = s4;
            for (int o = 1; o < 64; o <<= 1) { int v = __shfl_up(x, o); if (lane >= o) x += v; }
            if (lane == 63) wsum[w] = x;
        }
        __syncthreads();
        if (w == 0) {
            int v = (lane < 8) ? wsum[lane] : 0;
            for (int o = 1; o < 8; o <<= 1) { int u = __shfl_up(v, o); if (lane >= o) v += u; }
            if (lane < 8) wsum[lane] = v;               // inclusive wave totals
        }
        __syncthreads();
        if (t < 512) {
            int b = t * 4;
            int ex = ((w == 0) ? 0 : wsum[w - 1]) + x - s4;
            int o0 = ex, o1 = ex + l0, o2 = o1 + l1, o3 = o2 + l2;
            off_[b] = o0; off_[b + 1] = o1; off_[b + 2] = o2; off_[b + 3] = o3;
            cnt[b] = o0; cnt[b + 1] = o1; cnt[b + 2] = o2; cnt[b + 3] = o3;   // scatter cursor
        }
        __syncthreads();
        for (int i = t; i < n; i += 1024) {
            int4 k = kp4[i];
            int c = (k.z >> CSH) * NCX + (k.w >> CSH);
            int pos = atomicAdd(&cnt[c], 1);   // within-cell order nondeterministic; consumers commutative
            int2 v; v.x = (k.z << 16) | k.w; v.y = __float_as_int(sc[i]);
            lppL[pos] = v;
            sidxL[pos] = (unsigned short)i;
        }
        __syncthreads();
        // pixel-max + rep (min original index) per sorted point; dump to global
        for (int j = t; j < n; j += 1024) {
            int2 v = lppL[j];
            int c = ((v.x >> 16) >> CSH) * NCX + ((v.x & 0xFFFF) >> CSH);
            int lo = off_[c], hi = cnt[c];     // cnt = end cursor after scatter
            int pmax = v.y; int myi = sidxL[j]; int rep = 1;
            for (int u = lo; u < hi; ++u) {
                int2 wv = lppL[u];
                if (wv.x == v.x) {
                    if (wv.y > pmax) pmax = wv.y;
                    if ((int)sidxL[u] < myi) rep = 0;
                }
            }
            pbr[j] = (int)(((unsigned)pmax & 0x7FFFFFFFu) | (rep ? 0x80000000u : 0u));
            ppk[j] = v;
            sidx[j] = myi;
        }
        for (int c = t; c < NC; c += 1024) { celloff[c] = off_[c]; cellmax[c] = cmx[c]; }
        if (t == 0) celloff[NC] = n;
    } else {
        // correctness-only fallback (NC <= NCG): global scratch
        int* cntG = gscr; int* offG = gscr + NCG; int* cmxG = gscr + 2 * NCG;
        for (int i = t; i < NC; i += 1024) { cntG[i] = 0; cmxG[i] = 0; }
        __syncthreads();
        for (int i = t; i < n; i += 1024) {
            int4 k = kp4[i];
            int c = (k.z >> CSH) * NCX + (k.w >> CSH);
            atomicAdd(&cntG[c], 1);
            atomicMax(&cmxG[c], __float_as_int(sc[i]));
        }
        __syncthreads();
        if (t == 0) { int run = 0; for (int c = 0; c < NC; ++c) { offG[c] = run; run += cntG[c]; } }
        __syncthreads();
        for (int i = t; i < NC; i += 1024) cntG[i] = offG[i];
        __syncthreads();
        for (int i = t; i < n; i += 1024) {
            int4 k = kp4[i];
            int c = (k.z >> CSH) * NCX + (k.w >> CSH);
            int pos = atomicAdd(&cntG[c], 1);
            int2 v; v.x = (k.z << 16) | k.w; v.y = __float_as_int(sc[i]);
            ppk[pos] = v; sidx[pos] = i;
        }
        __syncthreads();
        for (int j = t; j < n; j += 1024) {
            int2 v = ppk[j];
            int c = ((v.x >> 16) >> CSH) * NCX + ((v.x & 0xFFFF) >> CSH);
            int lo = offG[c], hi = cntG[c];
            int pmax = v.y; int myi = sidx[j]; int rep = 1;
            for (int u = lo; u < hi; ++u) {
                int2 wv = ppk[u];
                if (wv.x == v.x) { if (wv.y > pmax) pmax = wv.y; if (sidx[u] < myi) rep = 0; }
            }
            pbr[j] = (int)(((unsigned)pmax & 0x7FFFFFFFu) | (rep ? 0x80000000u : 0u));
        }
        __syncthreads();
        for (int c = t; c < NC; c += 1024) { celloff[c] = offG[c]; cellmax[c] = cmxG[c]; }
        if (t == 0) celloff[NC] = n;
    }
    if (t == 0) {
        int nret = nret_[0];
        int mx = rows > cols ? rows : cols;
        int nr1 = nret > 1 ? nret : 1;
        int dvs = (int)sqrt((double)n / (double)nr1);   // Python int() truncation
        if (dvs < 1) dvs = 1;
        int high = mx / dvs; if (high < 1) high = 1;
        meta[0] = high / 2;                    // RMAX: no probed radius can exceed this
        meta[1] = NCX;
        meta[2] = NCY;
    }
}

// ---------------- K2: two-pass query ----------------
// Pass 1 (TPP=16/pt): rings 0-1 only. d <= 64 is provably exact -> emit.
// Else enqueue; Pass 2: one WAVE per hard point brute-forces all n LDS points
// (conflict-free stride-64), capped at RMAX+1.
template<bool LDSP>
__global__ __launch_bounds__(TPB, 1) void query_k(
    const int* __restrict__ meta,
    const int* __restrict__ celloff, const int* __restrict__ cellmax,
    const int2* __restrict__ ppk, const int* __restrict__ sidx,
    const int* __restrict__ pbr, int n, int* __restrict__ dd, int* __restrict__ hist) {
    __shared__ int2 lcell[NCLDS + 1];          // {off, maxbits}
    __shared__ int2 lpp[LDSP ? QLP : 1];       // packed points {(y<<16)|x, score_bits}
    __shared__ int hardq[64], hardpb[64];
    __shared__ int nhard;
    int t = threadIdx.x;
    int RMAX = meta[0], NCX = meta[1], NCY = meta[2];
    int NC = NCX * NCY;
    int gt = blockIdx.x * TPB + t;
    int q = gt >> 4, sub = gt & 15;
    bool act = q < n;
    if (t == 0) nhard = 0;

    // prefetch per-point globals BEFORE staging barrier
    int2 me; me.x = 0; me.y = 0;
    int idxv = 0, pbrv = 0, lo = 0, hi = 0, y = 0, x = 0, cy = 0, cx = 0;
    if (act) {
        me = ppk[q];
        idxv = sidx[q];
        pbrv = pbr[q];
        y = me.x >> 16; x = me.x & 0xFFFF;
        cy = y >> CSH;  cx = x >> CSH;
        int c0 = cy * NCX + cx;
        lo = celloff[c0]; hi = celloff[c0 + 1];
    }
    bool cellsL = (NC <= NCLDS);
    if (cellsL) {
        for (int i = t; i <= NC; i += TPB) {
            int2 v; v.x = celloff[i]; v.y = (i < NC) ? cellmax[i] : 0;
            lcell[i] = v;
        }
    }
    if constexpr (LDSP) {
        int nh = n >> 1;
        const int4* s4 = (const int4*)ppk;
        int4* d4 = (int4*)lpp;
        for (int i = t; i < nh; i += TPB) d4[i] = s4[i];
        if ((n & 1) && t == 0) lpp[n - 1] = ppk[n - 1];
    }
    __syncthreads();
    const int2* P = LDSP ? (const int2*)lpp : ppk;

    // ---- pass 1 ----
    if (act) {
        int pb = pbrv & 0x7FFFFFFF;
        int d = RMAX + 1;
        for (int j = lo + sub; j < hi; j += TPP) {       // ring 0: own cell
            int2 v = P[j];
            if (v.y > pb) {
                int dy = y - (v.x >> 16);    dy = dy < 0 ? -dy : dy;
                int dx = x - (v.x & 0xFFFF); dx = dx < 0 ? -dx : dx;
                int c = dy > dx ? dy : dx;
                if (c < d) d = c;
            }
        }
        d = min(d, __shfl_xor(d, 1)); d = min(d, __shfl_xor(d, 2));
        d = min(d, __shfl_xor(d, 4)); d = min(d, __shfl_xor(d, 8));
        if (d > 1) {                                     // LB(1)=1 < d: scan ring 1
            for (int e = sub; e < 8; e += TPP) {
                int a, b;
                if (e < 3)      { a = -1; b = -1 + e; }
                else if (e < 6) { a =  1; b = -1 + (e - 3); }
                else            { int ss = e - 6; a = 0; b = (ss & 1) ? 1 : -1; }
                int ccy = cy + a, ccx = cx + b;
                if (ccy < 0 || ccy >= NCY || ccx < 0 || ccx >= NCX) continue;
                int cc = ccy * NCX + ccx;
                int2 cm; int jhi;
                if (cellsL) { cm = lcell[cc]; jhi = lcell[cc + 1].x; }
                else { cm.x = celloff[cc]; cm.y = cellmax[cc]; jhi = celloff[cc + 1]; }
                if (cm.y <= pb) continue;                // no strictly-greater score here
                for (int j = cm.x; j < jhi; ++j) {
                    int2 v = P[j];
                    if (v.y > pb) {
                        int dy = y - (v.x >> 16);    dy = dy < 0 ? -dy : dy;
                        int dx = x - (v.x & 0xFFFF); dx = dx < 0 ? -dx : dx;
                        int c = dy > dx ? dy : dx;
                        if (c < d) d = c;
                    }
                }
            }
            d = min(d, __shfl_xor(d, 1)); d = min(d, __shfl_xor(d, 2));
            d = min(d, __shfl_xor(d, 4)); d = min(d, __shfl_xor(d, 8));
        }
        if (sub == 0) {
            if (d <= CSZ) {                              // exact: emit now
                dd[idxv] = d;
                if ((unsigned)pbrv >> 31)
                    atomicAdd(&hist[d < HSIZE ? d : HSIZE - 1], 1);
            } else {                                     // hard: queue for pass 2
                int p = atomicAdd(&nhard, 1);
                hardq[p] = q; hardpb[p] = pbrv;
            }
        }
    }
    __syncthreads();

    // ---- pass 2: one wave per hard point, brute force over all n points ----
    int wid = t >> 6, lane = t & 63;
    for (int h = wid; h < nhard; h += TPB / 64) {
        int hq = hardq[h];
        int hpbr = hardpb[h];
        int pb = hpbr & 0x7FFFFFFF;
        int2 hme = P[hq];
        int hy = hme.x >> 16, hx = hme.x & 0xFFFF;
        int d = RMAX + 1;
        for (int j = lane; j < n; j += 64) {             // conflict-free stride
            int2 v = P[j];
            if (v.y > pb) {
                int dy = hy - (v.x >> 16);    dy = dy < 0 ? -dy : dy;
                int dx = hx - (v.x & 0xFFFF); dx = dx < 0 ? -dx : dx;
                int c = dy > dx ? dy : dx;
                if (c < d) d = c;
            }
        }
        d = min(d, __shfl_xor(d, 1));  d = min(d, __shfl_xor(d, 2));
        d = min(d, __shfl_xor(d, 4));  d = min(d, __shfl_xor(d, 8));
        d = min(d, __shfl_xor(d, 16)); d = min(d, __shfl_xor(d, 32));
        if (lane == 0) {
            dd[sidx[hq]] = d;
            if ((unsigned)hpbr >> 31)
                atomicAdd(&hist[d < HSIZE ? d : HSIZE - 1], 1);
        }
    }
}

// ---------------- K3: binary-search replica + ordered select (one block) ----------------
__global__ __launch_bounds__(1024) void finish_k(
    const int* __restrict__ kp, const float* __restrict__ sc,
    const int* __restrict__ dd, const int* __restrict__ hist,
    const int* __restrict__ nret_, const int* __restrict__ rows_, const int* __restrict__ cols_,
    int n, float* __restrict__ out) {
    __shared__ int suf[HSIZE + 1];
    __shared__ int wsuf[16];
    __shared__ int aux[1024];
    __shared__ int wtK[16], wtN[16];
    __shared__ int rsh;
    int t = threadIdx.x, lane = t & 63, w = t >> 6;

    // suffix sums of hist via shfl (3 barriers): suf[v] = # pixels with d >= v
    int b0 = hist[2 * t], b1 = hist[2 * t + 1];
    int s = b0 + b1;
    int x = s;
    for (int o = 1; o < 64; o <<= 1) { int v = __shfl_down(x, o); if (lane + o < 64) x += v; }
    if (lane == 0) wsuf[w] = x;
    __syncthreads();
    if (w == 0) {
        int v = (lane < 16) ? wsuf[lane] : 0;
        for (int o = 1; o < 16; o <<= 1) { int u = __shfl_down(v, o); if (lane + o < 16) v += u; }
        if (lane < 16) wsuf[lane] = v;             // inclusive suffix of wave totals
    }
    __syncthreads();
    int S = x + ((w < 15) ? wsuf[w + 1] : 0);
    suf[2 * t] = S;
    suf[2 * t + 1] = S - b0;
    if (t == 0) suf[HSIZE] = 0;
    __syncthreads();

    if (t == 0) {
        int nret = nret_[0];
        int rows = rows_[0], cols = cols_[0];
        int kmin = (int)llround((double)nret * (1.0 - 0.1));
        int kmax = (int)llround((double)nret * (1.0 + 0.1));
        int mx = rows > cols ? rows : cols;
        int nr1 = nret > 1 ? nret : 1;
        int dvs = (int)sqrt((double)n / (double)nr1);
        if (dvs < 1) dvs = 1;
        int high = mx / dvs; if (high < 1) high = 1;
        int low = 1, prev_k = -1, r_final = -1;
        bool found = false;
        while (true) {
            int k = (low + high) / 2;
            if (k == prev_k || low > high) break;
            int r = k / 2;                               // == k_odd // 2 for both parities
            int cnt = (r + 1 <= HSIZE) ? suf[r + 1] : 0;
            if (cnt >= kmin && cnt <= kmax) { r_final = r; found = true; break; }
            else if (cnt < kmin) high = k - 1;
            else low = k + 1;
            prev_k = k;
        }
        if (!found) {
            int kfb = prev_k > 0 ? prev_k : 1;
            r_final = kfb / 2;
        }
        rsh = r_final;
    }
    __syncthreads();
    int r = rsh;
    int nret = nret_[0];

    // total kept points m
    int c = 0;
    for (int i = t; i < n; i += 1024) c += (dd[i] > r) ? 1 : 0;
    aux[t] = c;
    __syncthreads();
    for (int st = 512; st > 0; st >>= 1) {
        if (t < st) aux[t] += aux[t + st];
        __syncthreads();
    }
    int m = aux[0];
    __syncthreads();

    // ordered selection: kept ascending, pad with non-kept ascending, truncate at nret
    unsigned long long lanemask = (lane == 0) ? 0ull : (~0ull >> (64 - lane));
    int runK = 0, runN = 0;
    for (int bb = 0; bb < n; bb += 1024) {
        int i = bb + t;
        bool valid = i < n;
        bool f  = valid && (dd[i] > r);
        bool nf = valid && !f;
        unsigned long long mk = __ballot(f);
        unsigned long long mn = __ballot(nf);
        int pk = __popcll(mk & lanemask);
        int pn = __popcll(mn & lanemask);
        if (lane == 0) { wtK[w] = __popcll(mk); wtN[w] = __popcll(mn); }
        __syncthreads();
        int exK = runK + pk, exN = runN + pn;
        for (int u = 0; u < w; ++u) { exK += wtK[u]; exN += wtN[u]; }
        int ctK = 0, ctN = 0;
        for (int u = 0; u < 16; ++u) { ctK += wtK[u]; ctN += wtN[u]; }
        __syncthreads();
        if (valid) {
            int slot = -1;
            if (f) {
                if (exK < nret) slot = exK;
            } else if (nf && m < nret && (m + exN) < nret) {
                slot = m + exN;
            }
            if (slot >= 0) {
                out[slot * 4 + 0] = (float)kp[i * 4 + 0];
                out[slot * 4 + 1] = (float)kp[i * 4 + 1];
                out[slot * 4 + 2] = (float)kp[i * 4 + 2];
                out[slot * 4 + 3] = (float)kp[i * 4 + 3];
                out[nret * 4 + slot] = sc[i];
            }
        }
        runK += ctK;
        runN += ctN;
    }
}

extern "C" void kernel_launch(void* const* d_in, const int* in_sizes, int n_in,
                              void* d_out, int out_size, void* d_ws, size_t ws_size,
                              hipStream_t stream) {
    const int*   kp   = (const int*)d_in[0];
    const float* sc   = (const float*)d_in[1];
    const int*   nret = (const int*)d_in[2];
    const int*   rows = (const int*)d_in[3];
    const int*   cols = (const int*)d_in[4];
    int n = in_sizes[1];                       // number of points

    int* hist    = (int*)d_ws;                 // 2048
    int* meta    = hist + HSIZE;               // 16
    int* celloff = meta + 16;                  // NCG+16
    int* cellmax = celloff + NCG + 16;         // NCG
    int* gscr    = cellmax + NCG;              // 3*NCG (fallback scratch)
    int2* ppk    = (int2*)(gscr + 3 * NCG);    // n int2 (even int offset -> 8B aligned)
    int* sidx    = (int*)(ppk + n);            // n
    int* pbr     = sidx + n;                   // n
    int* dd      = pbr + n;                    // n
    float* out   = (float*)d_out;

    build_k<<<1, 1024, 0, stream>>>(kp, sc, nret, rows, cols, n,
                                    hist, meta, celloff, cellmax, ppk, sidx, pbr, gscr);
    int qblocks = (int)(((long long)n * TPP + TPB - 1) / TPB);   // 250 for n=10000
    if (n <= QLP)
        query_k<true><<<qblocks, TPB, 0, stream>>>(meta, celloff, cellmax, ppk, sidx, pbr, n, dd, hist);
    else
        query_k<false><<<qblocks, TPB, 0, stream>>>(meta, celloff, cellmax, ppk, sidx, pbr, n, dd, hist);
    finish_k<<<1, 1024, 0, stream>>>(kp, sc, dd, hist, nret, rows, cols, n, out);
}

// Round 12
// 80.969 us; speedup vs baseline: 1.3282x; 1.1753x over previous
//
#include <hip/hip_runtime.h>

#define HSIZE 2048          // d-histogram buckets
#define CSH   6             // cell shift (64 px cells)
#define CSZ   64
#define NCG   4096          // global cell-array capacity
#define NCLDS 2048          // build LDS cell capacity (this family: 34x60 = 2040)
#define BLP   10176         // build LDS point capacity
#define QLP   10176         // query LDS point capacity (81408 B -> 2 blocks/CU)
#define TPP   16            // threads per point
#define TPB   512           // 32 pts/block -> 313 blocks, ALL co-resident at 2/CU

// ---------------- K1: build (single workgroup) ----------------
// zero hist; counting-sort points into cells (ppk/sidx); gcell = {off, maxbits};
// pbr = pixelmax | rep<<31; meta = {RMAX, NCX, NCY}
__global__ __launch_bounds__(1024) void build_k(
    const int* __restrict__ kp, const float* __restrict__ sc,
    const int* __restrict__ nret_, const int* __restrict__ rows_, const int* __restrict__ cols_,
    int n, int* __restrict__ hist, int* __restrict__ meta,
    int2* __restrict__ gcell, int2* __restrict__ ppk, int* __restrict__ sidx,
    int* __restrict__ pbr, int* __restrict__ gscr) {
    __shared__ int2 lppL[BLP];
    __shared__ unsigned short sidxL[BLP];
    __shared__ int cnt[NCLDS];
    __shared__ int off_[NCLDS];
    __shared__ int cmx[NCLDS];
    __shared__ int wsum[8];
    int t = threadIdx.x, lane = t & 63, w = t >> 6;
    int rows = rows_[0], cols = cols_[0];
    int NCX = (cols + CSZ - 1) >> CSH;
    int NCY = (rows + CSZ - 1) >> CSH;
    int NC = NCX * NCY;
    bool fits = (NC <= NCLDS) && (n <= BLP);
    const int4* kp4 = (const int4*)kp;

    for (int i = t; i < HSIZE; i += 1024) hist[i] = 0;

    if (fits) {
        for (int i = t; i < NCLDS; i += 1024) { cnt[i] = 0; cmx[i] = 0; }
        __syncthreads();
        for (int i = t; i < n; i += 1024) {
            int4 k = kp4[i];
            int c = (k.z >> CSH) * NCX + (k.w >> CSH);
            atomicAdd(&cnt[c], 1);
            atomicMax(&cmx[c], __float_as_int(sc[i]));   // scores > 0: bit order == value order
        }
        __syncthreads();
        // exclusive scan over NCLDS=2048: first 512 threads, 4 cells each, shfl scans
        int s4 = 0, l0 = 0, l1 = 0, l2 = 0, l3 = 0, x = 0;
        if (t < 512) {
            int b = t * 4;
            l0 = cnt[b]; l1 = cnt[b + 1]; l2 = cnt[b + 2]; l3 = cnt[b + 3];
            s4 = l0 + l1 + l2 + l3;
            x = s4;
            for (int o = 1; o < 64; o <<= 1) { int v = __shfl_up(x, o); if (lane >= o) x += v; }
            if (lane == 63) wsum[w] = x;
        }
        __syncthreads();
        if (w == 0) {
            int v = (lane < 8) ? wsum[lane] : 0;
            for (int o = 1; o < 8; o <<= 1) { int u = __shfl_up(v, o); if (lane >= o) v += u; }
            if (lane < 8) wsum[lane] = v;               // inclusive wave totals
        }
        __syncthreads();
        if (t < 512) {
            int b = t * 4;
            int ex = ((w == 0) ? 0 : wsum[w - 1]) + x - s4;
            int o0 = ex, o1 = ex + l0, o2 = o1 + l1, o3 = o2 + l2;
            off_[b] = o0; off_[b + 1] = o1; off_[b + 2] = o2; off_[b + 3] = o3;
            cnt[b] = o0; cnt[b + 1] = o1; cnt[b + 2] = o2; cnt[b + 3] = o3;   // scatter cursor
        }
        __syncthreads();
        for (int i = t; i < n; i += 1024) {
            int4 k = kp4[i];
            int c = (k.z >> CSH) * NCX + (k.w >> CSH);
            int pos = atomicAdd(&cnt[c], 1);   // within-cell order nondeterministic; consumers commutative
            int2 v; v.x = (k.z << 16) | k.w; v.y = __float_as_int(sc[i]);
            lppL[pos] = v;
            sidxL[pos] = (unsigned short)i;
        }
        __syncthreads();
        // pixel-max + rep (own index is min among same-pixel) per sorted slot; dump to global
        for (int j = t; j < n; j += 1024) {
            int2 v = lppL[j];
            int c = ((v.x >> 16) >> CSH) * NCX + ((v.x & 0xFFFF) >> CSH);
            int lo = off_[c], hi = cnt[c];     // cnt = end cursor after scatter
            int pmax = v.y; int myi = sidxL[j]; int rep = 1;
            for (int u = lo; u < hi; ++u) {
                int2 wv = lppL[u];
                if (wv.x == v.x) {
                    if (wv.y > pmax) pmax = wv.y;
                    if ((int)sidxL[u] < myi) rep = 0;
                }
            }
            pbr[j] = (int)(((unsigned)pmax & 0x7FFFFFFFu) | (rep ? 0x80000000u : 0u));
            ppk[j] = v;
            sidx[j] = myi;                     // own original index
        }
        for (int c = t; c < NC; c += 1024) { int2 g; g.x = off_[c]; g.y = cmx[c]; gcell[c] = g; }
        if (t == 0) { int2 g; g.x = n; g.y = 0; gcell[NC] = g; }
    } else {
        // correctness-only fallback (NC <= NCG): global scratch
        int* cntG = gscr; int* offG = gscr + NCG; int* cmxG = gscr + 2 * NCG;
        for (int i = t; i < NC; i += 1024) { cntG[i] = 0; cmxG[i] = 0; }
        __syncthreads();
        for (int i = t; i < n; i += 1024) {
            int4 k = kp4[i];
            int c = (k.z >> CSH) * NCX + (k.w >> CSH);
            atomicAdd(&cntG[c], 1);
            atomicMax(&cmxG[c], __float_as_int(sc[i]));
        }
        __syncthreads();
        if (t == 0) { int run = 0; for (int c = 0; c < NC; ++c) { offG[c] = run; run += cntG[c]; } }
        __syncthreads();
        for (int i = t; i < NC; i += 1024) cntG[i] = offG[i];
        __syncthreads();
        for (int i = t; i < n; i += 1024) {
            int4 k = kp4[i];
            int c = (k.z >> CSH) * NCX + (k.w >> CSH);
            int pos = atomicAdd(&cntG[c], 1);
            int2 v; v.x = (k.z << 16) | k.w; v.y = __float_as_int(sc[i]);
            ppk[pos] = v; sidx[pos] = i;
        }
        __syncthreads();
        for (int j = t; j < n; j += 1024) {
            int2 v = ppk[j];
            int c = ((v.x >> 16) >> CSH) * NCX + ((v.x & 0xFFFF) >> CSH);
            int lo = offG[c], hi = cntG[c];
            int pmax = v.y; int myi = sidx[j]; int rep = 1;
            for (int u = lo; u < hi; ++u) {
                int2 wv = ppk[u];
                if (wv.x == v.x) { if (wv.y > pmax) pmax = wv.y; if (sidx[u] < myi) rep = 0; }
            }
            pbr[j] = (int)(((unsigned)pmax & 0x7FFFFFFFu) | (rep ? 0x80000000u : 0u));
        }
        __syncthreads();
        for (int c = t; c < NC; c += 1024) { int2 g; g.x = offG[c]; g.y = cmxG[c]; gcell[c] = g; }
        if (t == 0) { int2 g; g.x = n; g.y = 0; gcell[NC] = g; }
    }
    if (t == 0) {
        int nret = nret_[0];
        int mx = rows > cols ? rows : cols;
        int nr1 = nret > 1 ? nret : 1;
        int dvs = (int)sqrt((double)n / (double)nr1);   // Python int() truncation
        if (dvs < 1) dvs = 1;
        int high = mx / dvs; if (high < 1) high = 1;
        meta[0] = high / 2;                    // RMAX: no probed radius can exceed this
        meta[1] = NCX;
        meta[2] = NCY;
    }
}

// ---------------- K2: query (16 thr/pt; points in LDS; cells via global L1) ----------------
// LDS = 81408 B only -> 2 blocks/CU co-resident: 16 waves/CU hide the walk's latency chains.
template<bool LDSP>
__global__ __launch_bounds__(TPB, 2) void query_k(
    const int* __restrict__ meta, const int2* __restrict__ gcell,
    const int2* __restrict__ ppk, const int* __restrict__ sidx,
    const int* __restrict__ pbr, int n, int* __restrict__ dd, int* __restrict__ hist) {
    __shared__ int2 lpp[LDSP ? QLP : 1];       // packed points {(y<<16)|x, score_bits}
    int t = threadIdx.x;
    int RMAX = meta[0], NCX = meta[1], NCY = meta[2];
    int gt = blockIdx.x * TPB + t;
    int q = gt >> 4, sub = gt & 15;
    bool act = q < n;

    // prefetch per-point globals BEFORE staging barrier (latency hides under staging)
    int2 me; me.x = 0; me.y = 0;
    int idxv = 0, pbrv = 0, lo = 0, hi = 0, y = 0, x = 0, cy = 0, cx = 0;
    if (act) {
        me = ppk[q];
        idxv = sidx[q];
        pbrv = pbr[q];
        y = me.x >> 16; x = me.x & 0xFFFF;
        cy = y >> CSH;  cx = x >> CSH;
        int c0 = cy * NCX + cx;
        lo = gcell[c0].x; hi = gcell[c0 + 1].x;
    }
    if constexpr (LDSP) {
        int nh = n >> 1;
        const int4* s4 = (const int4*)ppk;
        int4* d4 = (int4*)lpp;
        for (int i = t; i < nh; i += TPB) d4[i] = s4[i];
        if ((n & 1) && t == 0) lpp[n - 1] = ppk[n - 1];
        __syncthreads();
    }
    if (act) {
        const int2* P = LDSP ? (const int2*)lpp : ppk;
        int pb = pbrv & 0x7FFFFFFF;                // pixel-max score bits
        int d = RMAX + 1;                          // "no higher within RMAX" sentinel
        for (int j = lo + sub; j < hi; j += TPP) { // ring 0: own cell
            int2 v = P[j];
            if (v.y > pb) {
                int dy = y - (v.x >> 16);    dy = dy < 0 ? -dy : dy;
                int dx = x - (v.x & 0xFFFF); dx = dx < 0 ? -dx : dx;
                int c = dy > dx ? dy : dx;
                if (c < d) d = c;
            }
        }
        d = min(d, __shfl_xor(d, 1)); d = min(d, __shfl_xor(d, 2));
        d = min(d, __shfl_xor(d, 4)); d = min(d, __shfl_xor(d, 8));

        for (int R = 1;; ++R) {                    // expanding rings
            int LB = (R - 1) * CSZ + 1;            // min possible distance from ring-R cells
            if (LB >= d) break;                    // covers d == RMAX+1 cap too
            for (int e = sub; e < 8 * R; e += TPP) {
                int a, b;
                if (e < 2 * R + 1)      { a = -R; b = -R + e; }
                else if (e < 4 * R + 2) { a =  R; b = -R + (e - (2 * R + 1)); }
                else { int ss = e - (4 * R + 2); a = -R + 1 + (ss >> 1); b = (ss & 1) ? R : -R; }
                int ccy = cy + a, ccx = cx + b;
                if (ccy < 0 || ccy >= NCY || ccx < 0 || ccx >= NCX) continue;
                int cc = ccy * NCX + ccx;
                int2 cm = gcell[cc];               // one 8B L1-hot probe: {off, max}
                if (cm.y <= pb) continue;          // no strictly-greater score in this cell
                int jhi = gcell[cc + 1].x;
                for (int j = cm.x; j < jhi; ++j) {
                    int2 v = P[j];
                    if (v.y > pb) {
                        int dy = y - (v.x >> 16);    dy = dy < 0 ? -dy : dy;
                        int dx = x - (v.x & 0xFFFF); dx = dx < 0 ? -dx : dx;
                        int c = dy > dx ? dy : dx;
                        if (c < d) d = c;
                    }
                }
            }
            d = min(d, __shfl_xor(d, 1)); d = min(d, __shfl_xor(d, 2));
            d = min(d, __shfl_xor(d, 4)); d = min(d, __shfl_xor(d, 8));
        }
        if (sub == 0) {
            dd[idxv] = d;                                  // single writer per point
            if ((unsigned)pbrv >> 31)                      // pixel representative
                atomicAdd(&hist[d < HSIZE ? d : HSIZE - 1], 1);
        }
    }
}

// ---------------- K3: binary-search replica + ordered select (one block) ----------------
__global__ __launch_bounds__(1024) void finish_k(
    const int* __restrict__ kp, const float* __restrict__ sc,
    const int* __restrict__ dd, const int* __restrict__ hist,
    const int* __restrict__ nret_, const int* __restrict__ rows_, const int* __restrict__ cols_,
    int n, float* __restrict__ out) {
    __shared__ int suf[HSIZE + 1];
    __shared__ int wsuf[16];
    __shared__ int aux[1024];
    __shared__ int wtK[16], wtN[16];
    __shared__ int rsh;
    int t = threadIdx.x, lane = t & 63, w = t >> 6;

    // suffix sums of hist via shfl (3 barriers): suf[v] = # pixels with d >= v
    int b0 = hist[2 * t], b1 = hist[2 * t + 1];
    int s = b0 + b1;
    int x = s;
    for (int o = 1; o < 64; o <<= 1) { int v = __shfl_down(x, o); if (lane + o < 64) x += v; }
    if (lane == 0) wsuf[w] = x;
    __syncthreads();
    if (w == 0) {
        int v = (lane < 16) ? wsuf[lane] : 0;
        for (int o = 1; o < 16; o <<= 1) { int u = __shfl_down(v, o); if (lane + o < 16) v += u; }
        if (lane < 16) wsuf[lane] = v;             // inclusive suffix of wave totals
    }
    __syncthreads();
    int S = x + ((w < 15) ? wsuf[w + 1] : 0);
    suf[2 * t] = S;
    suf[2 * t + 1] = S - b0;
    if (t == 0) suf[HSIZE] = 0;
    __syncthreads();

    if (t == 0) {
        int nret = nret_[0];
        int rows = rows_[0], cols = cols_[0];
        int kmin = (int)llround((double)nret * (1.0 - 0.1));
        int kmax = (int)llround((double)nret * (1.0 + 0.1));
        int mx = rows > cols ? rows : cols;
        int nr1 = nret > 1 ? nret : 1;
        int dvs = (int)sqrt((double)n / (double)nr1);
        if (dvs < 1) dvs = 1;
        int high = mx / dvs; if (high < 1) high = 1;
        int low = 1, prev_k = -1, r_final = -1;
        bool found = false;
        while (true) {
            int k = (low + high) / 2;
            if (k == prev_k || low > high) break;
            int r = k / 2;                               // == k_odd // 2 for both parities
            int cnt = (r + 1 <= HSIZE) ? suf[r + 1] : 0;
            if (cnt >= kmin && cnt <= kmax) { r_final = r; found = true; break; }
            else if (cnt < kmin) high = k - 1;
            else low = k + 1;
            prev_k = k;
        }
        if (!found) {
            int kfb = prev_k > 0 ? prev_k : 1;
            r_final = kfb / 2;
        }
        rsh = r_final;
    }
    __syncthreads();
    int r = rsh;
    int nret = nret_[0];

    // total kept points m
    int c = 0;
    for (int i = t; i < n; i += 1024) c += (dd[i] > r) ? 1 : 0;
    aux[t] = c;
    __syncthreads();
    for (int st = 512; st > 0; st >>= 1) {
        if (t < st) aux[t] += aux[t + st];
        __syncthreads();
    }
    int m = aux[0];
    __syncthreads();

    // ordered selection: kept ascending, pad with non-kept ascending, truncate at nret
    unsigned long long lanemask = (lane == 0) ? 0ull : (~0ull >> (64 - lane));
    int runK = 0, runN = 0;
    for (int bb = 0; bb < n; bb += 1024) {
        int i = bb + t;
        bool valid = i < n;
        bool f  = valid && (dd[i] > r);
        bool nf = valid && !f;
        unsigned long long mk = __ballot(f);
        unsigned long long mn = __ballot(nf);
        int pk = __popcll(mk & lanemask);
        int pn = __popcll(mn & lanemask);
        if (lane == 0) { wtK[w] = __popcll(mk); wtN[w] = __popcll(mn); }
        __syncthreads();
        int exK = runK + pk, exN = runN + pn;
        for (int u = 0; u < w; ++u) { exK += wtK[u]; exN += wtN[u]; }
        int ctK = 0, ctN = 0;
        for (int u = 0; u < 16; ++u) { ctK += wtK[u]; ctN += wtN[u]; }
        __syncthreads();
        if (valid) {
            int slot = -1;
            if (f) {
                if (exK < nret) slot = exK;
            } else if (nf && m < nret && (m + exN) < nret) {
                slot = m + exN;
            }
            if (slot >= 0) {
                out[slot * 4 + 0] = (float)kp[i * 4 + 0];
                out[slot * 4 + 1] = (float)kp[i * 4 + 1];
                out[slot * 4 + 2] = (float)kp[i * 4 + 2];
                out[slot * 4 + 3] = (float)kp[i * 4 + 3];
                out[nret * 4 + slot] = sc[i];
            }
        }
        runK += ctK;
        runN += ctN;
    }
}

extern "C" void kernel_launch(void* const* d_in, const int* in_sizes, int n_in,
                              void* d_out, int out_size, void* d_ws, size_t ws_size,
                              hipStream_t stream) {
    const int*   kp   = (const int*)d_in[0];
    const float* sc   = (const float*)d_in[1];
    const int*   nret = (const int*)d_in[2];
    const int*   rows = (const int*)d_in[3];
    const int*   cols = (const int*)d_in[4];
    int n = in_sizes[1];                       // number of points

    int* hist   = (int*)d_ws;                  // 2048
    int* meta   = hist + HSIZE;                // 16
    int2* gcell = (int2*)(meta + 16);          // NCG+16 int2 (even int offset -> 8B aligned)
    int* gscr   = (int*)(gcell + NCG + 16);    // 3*NCG (fallback scratch)
    int2* ppk   = (int2*)(gscr + 3 * NCG);     // n int2
    int* sidx   = (int*)(ppk + n);             // n
    int* pbr    = sidx + n;                    // n
    int* dd     = pbr + n;                     // n
    float* out  = (float*)d_out;

    build_k<<<1, 1024, 0, stream>>>(kp, sc, nret, rows, cols, n,
                                    hist, meta, gcell, ppk, sidx, pbr, gscr);
    int qblocks = (int)(((long long)n * TPP + TPB - 1) / TPB);   // 313 for n=10000
    if (n <= QLP)
        query_k<true><<<qblocks, TPB, 0, stream>>>(meta, gcell, ppk, sidx, pbr, n, dd, hist);
    else
        query_k<false><<<qblocks, TPB, 0, stream>>>(meta, gcell, ppk, sidx, pbr, n, dd, hist);
    finish_k<<<1, 1024, 0, stream>>>(kp, sc, dd, hist, nret, rows, cols, n, out);
}

// Round 13
// 75.885 us; speedup vs baseline: 1.4172x; 1.0670x over previous
//
#include <hip/hip_runtime.h>

#define HSIZE 2048          // d-histogram buckets; packed lo16=pixel reps, hi16=points (n<32768)
#define CSH   6             // cell shift (64 px cells)
#define CSZ   64
#define NCG   4096          // global cell-array capacity
#define NCLDS 2048          // LDS cell capacity (this family: 34x60 = 2040)
#define BLP   10176         // build LDS point capacity
#define QLP   10176         // query LDS point capacity (81408 B)
#define TPP   16            // threads per point
#define TPB   640           // 40 pts/block -> 250 blocks (one round over 256 CUs)

// ---------------- K1: build (single workgroup) ----------------
// zero hist; counting-sort points into cells (ppk/sidx); gcell = {off, maxbits} (+sentinel);
// pbr = pixelmax | rep<<31; meta = {RMAX, NCX, NCY}
__global__ __launch_bounds__(1024) void build_k(
    const int* __restrict__ kp, const float* __restrict__ sc,
    const int* __restrict__ nret_, const int* __restrict__ rows_, const int* __restrict__ cols_,
    int n, int* __restrict__ hist, int* __restrict__ meta,
    int2* __restrict__ gcell, int2* __restrict__ ppk, int* __restrict__ sidx,
    int* __restrict__ pbr, int* __restrict__ gscr) {
    __shared__ int2 lppL[BLP];
    __shared__ unsigned short sidxL[BLP];
    __shared__ int cnt[NCLDS];
    __shared__ int off_[NCLDS];
    __shared__ int cmx[NCLDS];
    __shared__ int wsum[8];
    int t = threadIdx.x, lane = t & 63, w = t >> 6;
    int rows = rows_[0], cols = cols_[0];
    int NCX = (cols + CSZ - 1) >> CSH;
    int NCY = (rows + CSZ - 1) >> CSH;
    int NC = NCX * NCY;
    bool fits = (NC <= NCLDS) && (n <= BLP);
    const int4* kp4 = (const int4*)kp;

    for (int i = t; i < HSIZE; i += 1024) hist[i] = 0;

    if (fits) {
        for (int i = t; i < NCLDS; i += 1024) { cnt[i] = 0; cmx[i] = 0; }
        __syncthreads();
        for (int i = t; i < n; i += 1024) {
            int4 k = kp4[i];
            int c = (k.z >> CSH) * NCX + (k.w >> CSH);
            atomicAdd(&cnt[c], 1);
            atomicMax(&cmx[c], __float_as_int(sc[i]));   // scores > 0: bit order == value order
        }
        __syncthreads();
        // exclusive scan over NCLDS=2048: first 512 threads, 4 cells each, shfl scans
        int s4 = 0, l0 = 0, l1 = 0, l2 = 0, l3 = 0, x = 0;
        if (t < 512) {
            int b = t * 4;
            l0 = cnt[b]; l1 = cnt[b + 1]; l2 = cnt[b + 2]; l3 = cnt[b + 3];
            s4 = l0 + l1 + l2 + l3;
            x = s4;
            for (int o = 1; o < 64; o <<= 1) { int v = __shfl_up(x, o); if (lane >= o) x += v; }
            if (lane == 63) wsum[w] = x;
        }
        __syncthreads();
        if (w == 0) {
            int v = (lane < 8) ? wsum[lane] : 0;
            for (int o = 1; o < 8; o <<= 1) { int u = __shfl_up(v, o); if (lane >= o) v += u; }
            if (lane < 8) wsum[lane] = v;               // inclusive wave totals
        }
        __syncthreads();
        if (t < 512) {
            int b = t * 4;
            int ex = ((w == 0) ? 0 : wsum[w - 1]) + x - s4;
            int o0 = ex, o1 = ex + l0, o2 = o1 + l1, o3 = o2 + l2;
            off_[b] = o0; off_[b + 1] = o1; off_[b + 2] = o2; off_[b + 3] = o3;
            cnt[b] = o0; cnt[b + 1] = o1; cnt[b + 2] = o2; cnt[b + 3] = o3;   // scatter cursor
        }
        __syncthreads();
        for (int i = t; i < n; i += 1024) {
            int4 k = kp4[i];
            int c = (k.z >> CSH) * NCX + (k.w >> CSH);
            int pos = atomicAdd(&cnt[c], 1);   // within-cell order nondeterministic; consumers commutative
            int2 v; v.x = (k.z << 16) | k.w; v.y = __float_as_int(sc[i]);
            lppL[pos] = v;
            sidxL[pos] = (unsigned short)i;
        }
        __syncthreads();
        // pixel-max + rep (own index is min among same-pixel) per sorted slot; dump to global
        for (int j = t; j < n; j += 1024) {
            int2 v = lppL[j];
            int c = ((v.x >> 16) >> CSH) * NCX + ((v.x & 0xFFFF) >> CSH);
            int lo = off_[c], hi = cnt[c];     // cnt = end cursor after scatter
            int pmax = v.y; int myi = sidxL[j]; int rep = 1;
            for (int u = lo; u < hi; ++u) {
                int2 wv = lppL[u];
                if (wv.x == v.x) {
                    if (wv.y > pmax) pmax = wv.y;
                    if ((int)sidxL[u] < myi) rep = 0;
                }
            }
            pbr[j] = (int)(((unsigned)pmax & 0x7FFFFFFFu) | (rep ? 0x80000000u : 0u));
            ppk[j] = v;
            sidx[j] = myi;                     // own original index
        }
        for (int c = t; c < NC; c += 1024) { int2 g; g.x = off_[c]; g.y = cmx[c]; gcell[c] = g; }
        if (t == 0) { int2 g; g.x = n; g.y = 0; gcell[NC] = g; }
    } else {
        // correctness-only fallback (NC <= NCG): global scratch
        int* cntG = gscr; int* offG = gscr + NCG; int* cmxG = gscr + 2 * NCG;
        for (int i = t; i < NC; i += 1024) { cntG[i] = 0; cmxG[i] = 0; }
        __syncthreads();
        for (int i = t; i < n; i += 1024) {
            int4 k = kp4[i];
            int c = (k.z >> CSH) * NCX + (k.w >> CSH);
            atomicAdd(&cntG[c], 1);
            atomicMax(&cmxG[c], __float_as_int(sc[i]));
        }
        __syncthreads();
        if (t == 0) { int run = 0; for (int c = 0; c < NC; ++c) { offG[c] = run; run += cntG[c]; } }
        __syncthreads();
        for (int i = t; i < NC; i += 1024) cntG[i] = offG[i];
        __syncthreads();
        for (int i = t; i < n; i += 1024) {
            int4 k = kp4[i];
            int c = (k.z >> CSH) * NCX + (k.w >> CSH);
            int pos = atomicAdd(&cntG[c], 1);
            int2 v; v.x = (k.z << 16) | k.w; v.y = __float_as_int(sc[i]);
            ppk[pos] = v; sidx[pos] = i;
        }
        __syncthreads();
        for (int j = t; j < n; j += 1024) {
            int2 v = ppk[j];
            int c = ((v.x >> 16) >> CSH) * NCX + ((v.x & 0xFFFF) >> CSH);
            int lo = offG[c], hi = cntG[c];
            int pmax = v.y; int myi = sidx[j]; int rep = 1;
            for (int u = lo; u < hi; ++u) {
                int2 wv = ppk[u];
                if (wv.x == v.x) { if (wv.y > pmax) pmax = wv.y; if (sidx[u] < myi) rep = 0; }
            }
            pbr[j] = (int)(((unsigned)pmax & 0x7FFFFFFFu) | (rep ? 0x80000000u : 0u));
        }
        __syncthreads();
        for (int c = t; c < NC; c += 1024) { int2 g; g.x = offG[c]; g.y = cmxG[c]; gcell[c] = g; }
        if (t == 0) { int2 g; g.x = n; g.y = 0; gcell[NC] = g; }
    }
    if (t == 0) {
        int nret = nret_[0];
        int mx = rows > cols ? rows : cols;
        int nr1 = nret > 1 ? nret : 1;
        int dvs = (int)sqrt((double)n / (double)nr1);   // Python int() truncation
        if (dvs < 1) dvs = 1;
        int high = mx / dvs; if (high < 1) high = 1;
        meta[0] = high / 2;                    // RMAX: no probed radius can exceed this
        meta[1] = NCX;
        meta[2] = NCY;
    }
}

// ---------------- K2: query (16 thr/pt; cells AND points in LDS = 97.8 KB) ----------------
template<bool LDSP>
__global__ __launch_bounds__(TPB, 1) void query_k(
    const int* __restrict__ meta, const int2* __restrict__ gcell,
    const int2* __restrict__ ppk, const int* __restrict__ sidx,
    const int* __restrict__ pbr, int n, int* __restrict__ dd, int* __restrict__ hist) {
    __shared__ int2 lcell[NCLDS + 1];          // {off, maxbits}
    __shared__ int2 lpp[LDSP ? QLP : 1];       // packed points {(y<<16)|x, score_bits}
    int t = threadIdx.x;
    int RMAX = meta[0], NCX = meta[1], NCY = meta[2];
    int NC = NCX * NCY;
    int gt = blockIdx.x * TPB + t;
    int q = gt >> 4, sub = gt & 15;
    bool act = q < n;

    // prefetch per-point globals BEFORE staging barrier (latency hides under staging)
    int2 me; me.x = 0; me.y = 0;
    int idxv = 0, pbrv = 0, lo = 0, hi = 0, y = 0, x = 0, cy = 0, cx = 0;
    if (act) {
        me = ppk[q];
        idxv = sidx[q];
        pbrv = pbr[q];
        y = me.x >> 16; x = me.x & 0xFFFF;
        cy = y >> CSH;  cx = x >> CSH;
        int c0 = cy * NCX + cx;
        lo = gcell[c0].x; hi = gcell[c0 + 1].x;
    }
    bool cellsL = (NC <= NCLDS);
    if (cellsL) {
        for (int i = t; i <= NC; i += TPB) lcell[i] = gcell[i];
    }
    if constexpr (LDSP) {
        int nh = n >> 1;
        const int4* s4 = (const int4*)ppk;
        int4* d4 = (int4*)lpp;
        for (int i = t; i < nh; i += TPB) d4[i] = s4[i];
        if ((n & 1) && t == 0) lpp[n - 1] = ppk[n - 1];
    }
    __syncthreads();

    if (act) {
        const int2* P = LDSP ? (const int2*)lpp : ppk;
        const int2* C = cellsL ? (const int2*)lcell : gcell;
        int pb = pbrv & 0x7FFFFFFF;                // pixel-max score bits
        int d = RMAX + 1;                          // "no higher within RMAX" sentinel
        for (int j = lo + sub; j < hi; j += TPP) { // ring 0: own cell
            int2 v = P[j];
            if (v.y > pb) {
                int dy = y - (v.x >> 16);    dy = dy < 0 ? -dy : dy;
                int dx = x - (v.x & 0xFFFF); dx = dx < 0 ? -dx : dx;
                int c = dy > dx ? dy : dx;
                if (c < d) d = c;
            }
        }
        d = min(d, __shfl_xor(d, 1)); d = min(d, __shfl_xor(d, 2));
        d = min(d, __shfl_xor(d, 4)); d = min(d, __shfl_xor(d, 8));

        for (int R = 1;; ++R) {                    // expanding rings
            int LB = (R - 1) * CSZ + 1;            // min possible distance from ring-R cells
            if (LB >= d) break;                    // covers d == RMAX+1 cap too
            for (int e = sub; e < 8 * R; e += TPP) {
                int a, b;
                if (e < 2 * R + 1)      { a = -R; b = -R + e; }
                else if (e < 4 * R + 2) { a =  R; b = -R + (e - (2 * R + 1)); }
                else { int ss = e - (4 * R + 2); a = -R + 1 + (ss >> 1); b = (ss & 1) ? R : -R; }
                int ccy = cy + a, ccx = cx + b;
                if (ccy < 0 || ccy >= NCY || ccx < 0 || ccx >= NCX) continue;
                int cc = ccy * NCX + ccx;
                int2 cm = C[cc];                   // one ds_read_b64: {off, max}
                if (cm.y <= pb) continue;          // no strictly-greater score in this cell
                int jhi = C[cc + 1].x;
                for (int j = cm.x; j < jhi; ++j) {
                    int2 v = P[j];
                    if (v.y > pb) {
                        int dy = y - (v.x >> 16);    dy = dy < 0 ? -dy : dy;
                        int dx = x - (v.x & 0xFFFF); dx = dx < 0 ? -dx : dx;
                        int c = dy > dx ? dy : dx;
                        if (c < d) d = c;
                    }
                }
            }
            d = min(d, __shfl_xor(d, 1)); d = min(d, __shfl_xor(d, 2));
            d = min(d, __shfl_xor(d, 4)); d = min(d, __shfl_xor(d, 8));
        }
        if (sub == 0) {
            dd[idxv] = d;                          // single writer per point
            int hb = d < HSIZE ? d : HSIZE - 1;    // packed: lo16 reps, hi16 points
            atomicAdd(&hist[hb], ((unsigned)pbrv >> 31) ? 0x10001 : 0x10000);
        }
    }
}

// ---------------- K3: binary-search replica + ordered select (one block) ----------------
__global__ __launch_bounds__(1024) void finish_k(
    const int* __restrict__ kp, const float* __restrict__ sc,
    const int* __restrict__ dd, const int* __restrict__ hist,
    const int* __restrict__ nret_, const int* __restrict__ rows_, const int* __restrict__ cols_,
    int n, float* __restrict__ out) {
    __shared__ int suf[HSIZE + 1];
    __shared__ int wsuf[16];
    __shared__ int wtK[16], wtN[16];
    __shared__ int rsh;
    int t = threadIdx.x, lane = t & 63, w = t >> 6;

    // packed suffix sums of hist (lo16 = reps, hi16 = points); no cross-carry: each sum <= n < 32768
    int b0 = hist[2 * t], b1 = hist[2 * t + 1];
    int s = b0 + b1;
    int x = s;
    for (int o = 1; o < 64; o <<= 1) { int v = __shfl_down(x, o); if (lane + o < 64) x += v; }
    if (lane == 0) wsuf[w] = x;
    __syncthreads();
    if (w == 0) {
        int v = (lane < 16) ? wsuf[lane] : 0;
        for (int o = 1; o < 16; o <<= 1) { int u = __shfl_down(v, o); if (lane + o < 16) v += u; }
        if (lane < 16) wsuf[lane] = v;             // inclusive suffix of wave totals
    }
    __syncthreads();
    int S = x + ((w < 15) ? wsuf[w + 1] : 0);
    suf[2 * t] = S;
    suf[2 * t + 1] = S - b0;
    if (t == 0) suf[HSIZE] = 0;
    __syncthreads();

    if (t == 0) {
        int nret = nret_[0];
        int rows = rows_[0], cols = cols_[0];
        int kmin = (int)llround((double)nret * (1.0 - 0.1));
        int kmax = (int)llround((double)nret * (1.0 + 0.1));
        int mx = rows > cols ? rows : cols;
        int nr1 = nret > 1 ? nret : 1;
        int dvs = (int)sqrt((double)n / (double)nr1);
        if (dvs < 1) dvs = 1;
        int high = mx / dvs; if (high < 1) high = 1;
        int low = 1, prev_k = -1, r_final = -1;
        bool found = false;
        while (true) {
            int k = (low + high) / 2;
            if (k == prev_k || low > high) break;
            int r = k / 2;                               // == k_odd // 2 for both parities
            int cnt = (r + 1 <= HSIZE) ? (suf[r + 1] & 0xFFFF) : 0;
            if (cnt >= kmin && cnt <= kmax) { r_final = r; found = true; break; }
            else if (cnt < kmin) high = k - 1;
            else low = k + 1;
            prev_k = k;
        }
        if (!found) {
            int kfb = prev_k > 0 ? prev_k : 1;
            r_final = kfb / 2;
        }
        rsh = r_final;
    }
    __syncthreads();
    int r = rsh;
    int nret = nret_[0];
    int m = (r + 1 <= HSIZE) ? (suf[r + 1] >> 16) : 0;   // total kept POINTS (hi16)

    // ordered selection: kept ascending, pad with non-kept ascending, truncate at nret
    unsigned long long lanemask = (lane == 0) ? 0ull : (~0ull >> (64 - lane));
    int runK = 0, runN = 0;
    for (int bb = 0; bb < n; bb += 1024) {
        int i = bb + t;
        bool valid = i < n;
        bool f  = valid && (dd[i] > r);
        bool nf = valid && !f;
        unsigned long long mk = __ballot(f);
        unsigned long long mn = __ballot(nf);
        int pk = __popcll(mk & lanemask);
        int pn = __popcll(mn & lanemask);
        if (lane == 0) { wtK[w] = __popcll(mk); wtN[w] = __popcll(mn); }
        __syncthreads();
        int exK = runK + pk, exN = runN + pn;
        for (int u = 0; u < w; ++u) { exK += wtK[u]; exN += wtN[u]; }
        int ctK = 0, ctN = 0;
        for (int u = 0; u < 16; ++u) { ctK += wtK[u]; ctN += wtN[u]; }
        __syncthreads();
        if (valid) {
            int slot = -1;
            if (f) {
                if (exK < nret) slot = exK;
            } else if (nf && m < nret && (m + exN) < nret) {
                slot = m + exN;
            }
            if (slot >= 0) {
                out[slot * 4 + 0] = (float)kp[i * 4 + 0];
                out[slot * 4 + 1] = (float)kp[i * 4 + 1];
                out[slot * 4 + 2] = (float)kp[i * 4 + 2];
                out[slot * 4 + 3] = (float)kp[i * 4 + 3];
                out[nret * 4 + slot] = sc[i];
            }
        }
        runK += ctK;
        runN += ctN;
    }
}

extern "C" void kernel_launch(void* const* d_in, const int* in_sizes, int n_in,
                              void* d_out, int out_size, void* d_ws, size_t ws_size,
                              hipStream_t stream) {
    const int*   kp   = (const int*)d_in[0];
    const float* sc   = (const float*)d_in[1];
    const int*   nret = (const int*)d_in[2];
    const int*   rows = (const int*)d_in[3];
    const int*   cols = (const int*)d_in[4];
    int n = in_sizes[1];                       // number of points

    int* hist   = (int*)d_ws;                  // 2048
    int* meta   = hist + HSIZE;                // 16
    int2* gcell = (int2*)(meta + 16);          // NCG+16 int2 (even int offset -> 8B aligned)
    int* gscr   = (int*)(gcell + NCG + 16);    // 3*NCG (fallback scratch)
    int2* ppk   = (int2*)(gscr + 3 * NCG);     // n int2
    int* sidx   = (int*)(ppk + n);             // n
    int* pbr    = sidx + n;                    // n
    int* dd     = pbr + n;                     // n
    float* out  = (float*)d_out;

    build_k<<<1, 1024, 0, stream>>>(kp, sc, nret, rows, cols, n,
                                    hist, meta, gcell, ppk, sidx, pbr, gscr);
    int qblocks = (int)(((long long)n * TPP + TPB - 1) / TPB);   // 250 for n=10000
    if (n <= QLP)
        query_k<true><<<qblocks, TPB, 0, stream>>>(meta, gcell, ppk, sidx, pbr, n, dd, hist);
    else
        query_k<false><<<qblocks, TPB, 0, stream>>>(meta, gcell, ppk, sidx, pbr, n, dd, hist);
    finish_k<<<1, 1024, 0, stream>>>(kp, sc, dd, hist, nret, rows, cols, n, out);
}